// Round 1
// baseline (557.245 us; speedup 1.0000x reference)
//
#include <hip/hip_runtime.h>
#include <hip/hip_bf16.h>
#include <type_traits>

typedef __hip_bfloat16 bf16;

#define IN_DIM 256
#define NHID 32
#define HEADS 4
#define OUT_DIM 128
#define HC 128   // HEADS*NHID == OUT_DIM

typedef __attribute__((ext_vector_type(8))) __bf16 bf16x8_t;
typedef __attribute__((ext_vector_type(4))) float f32x4_t;

__device__ __forceinline__ float bf2f(bf16 v) { return __bfloat162float(v); }

// ---------------- dtype detection ----------------
// flag = 1 -> float32 inputs, flag = 0 -> bf16 inputs.
__global__ void k_detect(const unsigned int* __restrict__ x, int* __restrict__ flag) {
    int t = threadIdx.x;
    int cnt = 0;
    for (int i = t; i < 4096; i += 256) {
        unsigned u = x[(size_t)i * 64];
        unsigned e = (u >> 7) & 0xFF;
        cnt += (e >= 100 && e < 130) ? 1 : 0;
    }
    __shared__ int sh[256];
    sh[t] = cnt;
    __syncthreads();
    for (int off = 128; off > 0; off >>= 1) {
        if (t < off) sh[t] += sh[t + off];
        __syncthreads();
    }
    if (t == 0) *flag = (sh[0] < 2048) ? 1 : 0;
}

// generic convert (bf16 or f32 -> f32), flag-branched per element
__global__ void k_cvt(const void* __restrict__ in, float* __restrict__ out, int nelem,
                      const int* __restrict__ flag) {
    int i = blockIdx.x * blockDim.x + threadIdx.x;
    if (i >= nelem) return;
    if (*flag) out[i] = ((const float*)in)[i];
    else out[i] = bf2f(((const bf16*)in)[i]);
}

// build B^T bf16 [128][256] from w1f f32 [256][128]
__global__ void k_prep_b1t(const float* __restrict__ w, bf16* __restrict__ bt) {
    int i = blockIdx.x * 256 + threadIdx.x;   // over 128*256
    if (i >= 128 * 256) return;
    int c = i >> 8, k = i & 255;
    bt[i] = __float2bfloat16(w[k * 128 + c]);
}

// build B2^T bf16 [128][256] = [W2^T | W2^T] from w2f f32 [128][128]
__global__ void k_prep_b2t(const float* __restrict__ w, bf16* __restrict__ bt) {
    int i = blockIdx.x * 256 + threadIdx.x;
    if (i >= 128 * 256) return;
    int c = i >> 8, k = i & 255;
    bt[i] = __float2bfloat16(w[(k & 127) * 128 + c]);
}

// ---------------- CSR build ----------------

__global__ void k_degree(const int* __restrict__ dst, int E, int* __restrict__ deg) {
    int e = blockIdx.x * blockDim.x + threadIdx.x;
    if (e < E) atomicAdd(&deg[dst[e]], 1);
}

__global__ void k_blocksum(const int* __restrict__ deg, int n, int* __restrict__ bsum) {
    __shared__ int sdata[256];
    int i = blockIdx.x * 256 + threadIdx.x;
    int v = (i < n) ? deg[i] : 0;
    sdata[threadIdx.x] = v;
    __syncthreads();
    for (int off = 128; off > 0; off >>= 1) {
        if (threadIdx.x < off) sdata[threadIdx.x] += sdata[threadIdx.x + off];
        __syncthreads();
    }
    if (threadIdx.x == 0) bsum[blockIdx.x] = sdata[0];
}

__global__ void k_scan_bsum(int* bsum, int nb) {
    __shared__ int buf[256];
    int t = threadIdx.x;
    int v = (t < nb) ? bsum[t] : 0;
    buf[t] = v;
    __syncthreads();
    for (int off = 1; off < 256; off <<= 1) {
        int add = (t >= off) ? buf[t - off] : 0;
        __syncthreads();
        buf[t] += add;
        __syncthreads();
    }
    if (t < nb) bsum[t] = buf[t] - v;   // exclusive
}

__global__ void k_scan_final(const int* __restrict__ deg, int n,
                             const int* __restrict__ bsum, int* __restrict__ rowptr) {
    __shared__ int buf[256];
    int t = threadIdx.x;
    int i = blockIdx.x * 256 + t;
    int v = (i < n) ? deg[i] : 0;
    buf[t] = v;
    __syncthreads();
    for (int off = 1; off < 256; off <<= 1) {
        int add = (t >= off) ? buf[t - off] : 0;
        __syncthreads();
        buf[t] += add;
        __syncthreads();
    }
    int excl = bsum[blockIdx.x] + buf[t] - v;
    if (i < n) rowptr[i] = excl;
    if (i == n - 1) rowptr[n] = excl + v;
}

__global__ void k_fill(const int* __restrict__ src, const int* __restrict__ dst, int E,
                       const int* __restrict__ rowptr, int* __restrict__ cursor,
                       int* __restrict__ col) {
    int e = blockIdx.x * blockDim.x + threadIdx.x;
    if (e < E) {
        int d = dst[e];
        int pos = atomicAdd(&cursor[d], 1);
        col[rowptr[d] + pos] = src[e];
    }
}

// ---------------- MFMA GEMM: C[n,128] = A[n,256]_bf16 @ B[256,128]_bf16 ----------------
// Bt is B transposed: [128 cols][256 k] row-major bf16 (contiguous K for frag loads).
// block = 256 threads = 4 waves; block tile = 32 rows x 128 cols; full K in regs.
// wave w -> cols [w*32, w*32+32); per wave: 2 row-tiles x 2 col-tiles of 16x16,
// K = 8 steps of 32. A frags: 64 VGPR, B frags: 64 VGPR, acc: 16 VGPR.

__global__ void __launch_bounds__(256, 2)
k_gemm_mfma(const bf16* __restrict__ A, const bf16* __restrict__ Bt,
            float* __restrict__ C, int n,
            const int* __restrict__ flag, int want) {
    if (want >= 0 && *flag != want) return;
    int t = threadIdx.x;
    int wave = t >> 6, lane = t & 63;
    int l15 = lane & 15, lg = lane >> 4;        // lg = 0..3 (k-group / row-group)
    int row0 = blockIdx.x * 32;

    // B fragments: lane holds Bt[col][ks*32 + lg*8 .. +7]
    bf16x8_t b[2][8];
#pragma unroll
    for (int ct = 0; ct < 2; ct++) {
        int bn = wave * 32 + ct * 16 + l15;
        const bf16* bp = &Bt[(size_t)bn * 256 + lg * 8];
#pragma unroll
        for (int ks = 0; ks < 8; ks++)
            b[ct][ks] = *(const bf16x8_t*)(bp + ks * 32);
    }
    // A fragments: lane holds A[row][ks*32 + lg*8 .. +7]
    bf16x8_t a[2][8];
#pragma unroll
    for (int rt = 0; rt < 2; rt++) {
        int ar = row0 + rt * 16 + l15;
        if (ar >= n) ar = n - 1;               // clamp (stores are guarded)
        const bf16* ap = &A[(size_t)ar * 256 + lg * 8];
#pragma unroll
        for (int ks = 0; ks < 8; ks++)
            a[rt][ks] = *(const bf16x8_t*)(ap + ks * 32);
    }

    f32x4_t acc[2][2];
#pragma unroll
    for (int rt = 0; rt < 2; rt++)
#pragma unroll
        for (int ct = 0; ct < 2; ct++)
            acc[rt][ct] = (f32x4_t){0.f, 0.f, 0.f, 0.f};

#pragma unroll
    for (int ks = 0; ks < 8; ks++)
#pragma unroll
        for (int rt = 0; rt < 2; rt++)
#pragma unroll
            for (int ct = 0; ct < 2; ct++)
                acc[rt][ct] = __builtin_amdgcn_mfma_f32_16x16x32_bf16(
                    a[rt][ks], b[ct][ks], acc[rt][ct], 0, 0, 0);

    // C/D layout (verified): col = lane&15, row = (lane>>4)*4 + reg
#pragma unroll
    for (int rt = 0; rt < 2; rt++) {
#pragma unroll
        for (int r = 0; r < 4; r++) {
            int row = row0 + rt * 16 + lg * 4 + r;
            if (row < n) {
#pragma unroll
                for (int ct = 0; ct < 2; ct++) {
                    int colx = wave * 32 + ct * 16 + l15;
                    C[(size_t)row * 128 + colx] = acc[rt][ct][r];
                }
            }
        }
    }
}

// ---------------- fallback fp32 vector GEMM (f32-input path only) ----------------

template <typename TA>
__global__ void k_gemm(const TA* __restrict__ A, const float* __restrict__ B,
                       float* __restrict__ C, int n, int K,
                       const int* __restrict__ flag, int want) {
    if (want >= 0 && *flag != want) return;
    extern __shared__ float a_lds[];   // 16*K floats
    int t = threadIdx.x;
    int row0 = blockIdx.x * 16;
    for (int idx = t; idx < 16 * K; idx += 256) {
        int r = idx / K, k = idx - r * K;
        int gr = row0 + r;
        float v = 0.f;
        if (gr < n) {
            if constexpr (std::is_same<TA, bf16>::value) v = bf2f(A[(size_t)gr * K + k]);
            else v = A[(size_t)gr * K + k];
        }
        a_lds[idx] = v;
    }
    __syncthreads();
    int col = t & 127, rg = t >> 7;
    float acc[8] = {0.f, 0.f, 0.f, 0.f, 0.f, 0.f, 0.f, 0.f};
    for (int k = 0; k < K; k += 8) {
        float b[8];
#pragma unroll
        for (int kk = 0; kk < 8; kk++) b[kk] = B[(k + kk) * HC + col];
#pragma unroll
        for (int r = 0; r < 8; r++) {
            const float* ap = &a_lds[(rg * 8 + r) * K + k];
            float4 a0 = *(const float4*)ap;
            float4 a1 = *(const float4*)(ap + 4);
            acc[r] += a0.x * b[0] + a0.y * b[1] + a0.z * b[2] + a0.w * b[3]
                    + a1.x * b[4] + a1.y * b[5] + a1.z * b[6] + a1.w * b[7];
        }
    }
#pragma unroll
    for (int r = 0; r < 8; r++) {
        int gr = row0 + rg * 8 + r;
        if (gr < n) C[(size_t)gr * HC + col] = acc[r];
    }
}

// ---------------- attention coefficients: alpha_s/alpha_d [n,H] ----------------

template <int H, int C>
__global__ void k_alpha(const float* __restrict__ h, const float* __restrict__ a_src,
                        const float* __restrict__ a_dst, int n,
                        float* __restrict__ as, float* __restrict__ ad) {
    int i = blockIdx.x * blockDim.x + threadIdx.x;   // (node, head)
    if (i >= n * H) return;
    int node = i / H, hh = i - node * H;
    const float* hp = &h[(size_t)node * (H * C) + hh * C];
    float ss = 0.f, sd = 0.f;
#pragma unroll
    for (int c = 0; c < C; c++) {
        float v = hp[c];
        ss += v * a_src[hh * C + c];
        sd += v * a_dst[hh * C + c];
    }
    as[i] = ss;
    ad[i] = sd;
}

// ---------------- aggregation: softmax over incoming edges + weighted sum ----------------
// one block (128 threads) per destination node; H*C must be 128.
// OMODE: 0 = f32 out [n,128]; 1 = bf16 out [n,128]; 2 = split hi/lo bf16 out [n,256]
// (mode 2 feeds the layer-2 MFMA GEMM: hi = bf16(val), lo = bf16(val - hi))

template <int H, int C, bool ELU_OUT, int OMODE>
__global__ void k_agg(const float* __restrict__ feat,  // [n, H*C]
                      const float* __restrict__ as,    // [n, H]
                      const float* __restrict__ ad,    // [n, H]
                      const int* __restrict__ rowptr,
                      const int* __restrict__ col,
                      const float* __restrict__ bias,  // [H*C]
                      void* __restrict__ out_, int n,
                      const int* __restrict__ flag, int want) {
    if (want >= 0 && *flag != want) return;
    constexpr int HC_ = H * C;
    int node = blockIdx.x;
    int t = threadIdx.x;        // 0..127 channel id
    int h = t / C;
    __shared__ float p_lds[64 * H];
    __shared__ int src_lds[64];
    __shared__ float s_sh[H];
    __shared__ float ad_sh[H];
    if (t < H) ad_sh[t] = ad[node * H + t];
    __syncthreads();
    int begin = rowptr[node], end = rowptr[node + 1];
    int total = end - begin + 1;   // + self-loop (placed last)
    float acc = 0.f;
    float s_loc[H];
#pragma unroll
    for (int hh = 0; hh < H; hh++) s_loc[hh] = 0.f;
    for (int base = 0; base < total; base += 64) {
        int cl = min(64, total - base);
        if (t < 64) {
            int j = base + t;
            if (j < total) {
                int s = (j < total - 1) ? col[begin + j] : node;
                src_lds[t] = s;
#pragma unroll
                for (int hh = 0; hh < H; hh++) {
                    float e = as[s * H + hh] + ad_sh[hh];
                    e = (e > 0.f) ? e : 0.2f * e;
                    float p = __expf(e);
                    p_lds[t * H + hh] = p;
                    s_loc[hh] += p;
                }
            }
        }
        __syncthreads();
        for (int j = 0; j < cl; j++) {
            acc += p_lds[j * H + h] * feat[(size_t)src_lds[j] * HC_ + t];
        }
        __syncthreads();
    }
    if (t < 64) {
#pragma unroll
        for (int hh = 0; hh < H; hh++) {
            float v = s_loc[hh];
#pragma unroll
            for (int off = 32; off > 0; off >>= 1) v += __shfl_xor(v, off);
            if (t == 0) s_sh[hh] = v;
        }
    }
    __syncthreads();
    float val = acc / (s_sh[h] + 1e-16f) + bias[t];
    if (ELU_OUT) val = (val > 0.f) ? val : expm1f(val);
    if constexpr (OMODE == 0) {
        ((float*)out_)[(size_t)node * HC_ + t] = val;
    } else if constexpr (OMODE == 1) {
        ((bf16*)out_)[(size_t)node * HC_ + t] = __float2bfloat16(val);
    } else {
        bf16 hi = __float2bfloat16(val);
        float lo = val - bf2f(hi);
        bf16* o = (bf16*)out_;
        o[(size_t)node * (2 * HC_) + t] = hi;
        o[(size_t)node * (2 * HC_) + HC_ + t] = __float2bfloat16(lo);
    }
}

// ---------------- launch ----------------

extern "C" void kernel_launch(void* const* d_in, const int* in_sizes, int n_in,
                              void* d_out, int out_size, void* d_ws, size_t ws_size,
                              hipStream_t stream) {
    const void* x  = d_in[0];
    const int*  ei = (const int*)d_in[1];

    int n = in_sizes[0] / IN_DIM;   // 50000
    int E = in_sizes[1] / 2;        // 800000
    const int* src = ei;
    const int* dst = ei + E;

    // workspace carve (256B aligned)
    char* w = (char*)d_ws;
    auto alloc = [&](size_t bytes) -> void* {
        void* p = (void*)w;
        w += (bytes + 255) / 256 * 256;
        return p;
    };
    int*   flag   = (int*)alloc(256);
    float* w1f    = (float*)alloc((size_t)IN_DIM * HC * 4);
    float* as1w   = (float*)alloc(HEADS * NHID * 4);
    float* ad1w   = (float*)alloc(HEADS * NHID * 4);
    float* b1f    = (float*)alloc(HC * 4);
    float* w2f    = (float*)alloc((size_t)HC * OUT_DIM * 4);
    float* as2w   = (float*)alloc(OUT_DIM * 4);
    float* ad2w   = (float*)alloc(OUT_DIM * 4);
    float* b2f    = (float*)alloc(OUT_DIM * 4);
    bf16*  b1t    = (bf16*)alloc((size_t)128 * 256 * 2);   // W1^T bf16 [128][256]
    bf16*  b2t    = (bf16*)alloc((size_t)128 * 256 * 2);   // [W2^T|W2^T] bf16 [128][256]
    float* h1     = (float*)alloc((size_t)n * HC * 4);   // layer1 features; reused as h2
    float* hmid   = (float*)alloc((size_t)n * HC * 4);   // post-ELU layer1 (f32 path) / split-bf16 A2 (bf16 path)
    float* as1    = (float*)alloc((size_t)n * HEADS * 4);
    float* ad1    = (float*)alloc((size_t)n * HEADS * 4);
    float* as2    = (float*)alloc((size_t)n * 4);
    float* ad2    = (float*)alloc((size_t)n * 4);
    int*   deg    = (int*)alloc((size_t)n * 4);
    int*   rowptr = (int*)alloc((size_t)(n + 1) * 4);
    int*   cursor = (int*)alloc((size_t)n * 4);
    int*   colv   = (int*)alloc((size_t)E * 4);
    int*   bsum   = (int*)alloc(256 * 4);
    float* h2 = h1;               // reuse
    bf16*  a2 = (bf16*)hmid;      // alias: [n][256] bf16 == [n][128] f32 in bytes

    k_detect<<<1, 256, 0, stream>>>((const unsigned int*)x, flag);

    // convert small weight tensors to fp32
    struct CvtJob { const void* in; float* out; int ne; };
    CvtJob jobs[8] = {
        {d_in[2], w1f,  IN_DIM * HC},
        {d_in[3], as1w, HEADS * NHID},
        {d_in[4], ad1w, HEADS * NHID},
        {d_in[5], b1f,  HC},
        {d_in[6], w2f,  HC * OUT_DIM},
        {d_in[7], as2w, OUT_DIM},
        {d_in[8], ad2w, OUT_DIM},
        {d_in[9], b2f,  OUT_DIM},
    };
    for (int j = 0; j < 8; j++)
        k_cvt<<<(jobs[j].ne + 255) / 256, 256, 0, stream>>>(jobs[j].in, jobs[j].out, jobs[j].ne, flag);

    // bf16 transposed weight panels for the MFMA path
    k_prep_b1t<<<128, 256, 0, stream>>>(w1f, b1t);
    k_prep_b2t<<<128, 256, 0, stream>>>(w2f, b2t);

    hipMemsetAsync(deg, 0, (size_t)n * 4, stream);
    hipMemsetAsync(cursor, 0, (size_t)n * 4, stream);

    int nb = (n + 255) / 256;   // 196 <= 256
    k_degree<<<(E + 255) / 256, 256, 0, stream>>>(dst, E, deg);
    k_blocksum<<<nb, 256, 0, stream>>>(deg, n, bsum);
    k_scan_bsum<<<1, 256, 0, stream>>>(bsum, nb);
    k_scan_final<<<nb, 256, 0, stream>>>(deg, n, bsum, rowptr);
    k_fill<<<(E + 255) / 256, 256, 0, stream>>>(src, dst, E, rowptr, cursor, colv);

    // layer 1 — MFMA for bf16 inputs (timed path), vector fallback for f32
    k_gemm_mfma<<<(n + 31) / 32, 256, 0, stream>>>((const bf16*)x, b1t, h1, n, flag, 0);
    k_gemm<float><<<(n + 15) / 16, 256, 16 * IN_DIM * 4, stream>>>(
        (const float*)x, w1f, h1, n, IN_DIM, flag, 1);
    k_alpha<HEADS, NHID><<<((size_t)n * HEADS + 255) / 256, 256, 0, stream>>>(h1, as1w, ad1w, n, as1, ad1);
    // bf16 path: write split hi/lo bf16 A2 for the layer-2 MFMA GEMM
    k_agg<HEADS, NHID, true, 2><<<n, 128, 0, stream>>>(h1, as1, ad1, rowptr, colv, b1f, a2, n, flag, 0);
    // f32 path: plain f32 hmid
    k_agg<HEADS, NHID, true, 0><<<n, 128, 0, stream>>>(h1, as1, ad1, rowptr, colv, b1f, hmid, n, flag, 1);

    // layer 2 — MFMA split-bf16 (K=256: [hi|lo] @ [W2;W2]) for bf16 path
    k_gemm_mfma<<<(n + 31) / 32, 256, 0, stream>>>(a2, b2t, h2, n, flag, 0);
    k_gemm<float><<<(n + 15) / 16, 256, 16 * HC * 4, stream>>>(hmid, w2f, h2, n, HC, flag, 1);
    k_alpha<1, OUT_DIM><<<(n + 255) / 256, 256, 0, stream>>>(h2, as2w, ad2w, n, as2, ad2);
    // output dual-launched on dtype (ref propagates input dtype to output)
    k_agg<1, OUT_DIM, false, 1><<<n, 128, 0, stream>>>(h2, as2, ad2, rowptr, colv, b2f, d_out, n, flag, 0);
    k_agg<1, OUT_DIM, false, 0><<<n, 128, 0, stream>>>(h2, as2, ad2, rowptr, colv, b2f, d_out, n, flag, 1);
}

// Round 3
// 478.022 us; speedup vs baseline: 1.1657x; 1.1657x over previous
//
#include <hip/hip_runtime.h>
#include <hip/hip_bf16.h>
#include <type_traits>

typedef __hip_bfloat16 bf16;

#define IN_DIM 256
#define NHID 32
#define HEADS 4
#define OUT_DIM 128
#define HC 128   // HEADS*NHID == OUT_DIM

typedef __attribute__((ext_vector_type(8))) __bf16 bf16x8_t;
typedef __attribute__((ext_vector_type(4))) float f32x4_t;

__device__ __forceinline__ float bf2f(bf16 v) { return __bfloat162float(v); }

// ---------------- dtype detection ----------------
// flag = 1 -> float32 inputs, flag = 0 -> bf16 inputs.
__global__ void k_detect(const unsigned int* __restrict__ x, int* __restrict__ flag) {
    int t = threadIdx.x;
    int cnt = 0;
    for (int i = t; i < 4096; i += 256) {
        unsigned u = x[(size_t)i * 64];
        unsigned e = (u >> 7) & 0xFF;
        cnt += (e >= 100 && e < 130) ? 1 : 0;
    }
    __shared__ int sh[256];
    sh[t] = cnt;
    __syncthreads();
    for (int off = 128; off > 0; off >>= 1) {
        if (t < off) sh[t] += sh[t + off];
        __syncthreads();
    }
    if (t == 0) *flag = (sh[0] < 2048) ? 1 : 0;
}

// generic convert (bf16 or f32 -> f32), flag-branched per element
__global__ void k_cvt(const void* __restrict__ in, float* __restrict__ out, int nelem,
                      const int* __restrict__ flag) {
    int i = blockIdx.x * blockDim.x + threadIdx.x;
    if (i >= nelem) return;
    if (*flag) out[i] = ((const float*)in)[i];
    else out[i] = bf2f(((const bf16*)in)[i]);
}

// build split-bf16 transposed panels: w f32 [K][128] -> bth/btl [128][K] bf16
// bth = bf16(w), btl = bf16(w - f32(bth))
__global__ void k_prep_bt(const float* __restrict__ w, __bf16* __restrict__ bth,
                          __bf16* __restrict__ btl, int K) {
    int i = blockIdx.x * 256 + threadIdx.x;
    if (i >= 128 * K) return;
    int c = i / K, k = i - c * K;
    float v = w[k * 128 + c];
    __bf16 h = (__bf16)v;
    bth[i] = h;
    btl[i] = (__bf16)(v - (float)h);
}

// ---------------- CSR build ----------------

__global__ void k_degree(const int* __restrict__ dst, int E, int* __restrict__ deg) {
    int e = blockIdx.x * blockDim.x + threadIdx.x;
    if (e < E) atomicAdd(&deg[dst[e]], 1);
}

__global__ void k_blocksum(const int* __restrict__ deg, int n, int* __restrict__ bsum) {
    __shared__ int sdata[256];
    int i = blockIdx.x * 256 + threadIdx.x;
    int v = (i < n) ? deg[i] : 0;
    sdata[threadIdx.x] = v;
    __syncthreads();
    for (int off = 128; off > 0; off >>= 1) {
        if (threadIdx.x < off) sdata[threadIdx.x] += sdata[threadIdx.x + off];
        __syncthreads();
    }
    if (threadIdx.x == 0) bsum[blockIdx.x] = sdata[0];
}

__global__ void k_scan_bsum(int* bsum, int nb) {
    __shared__ int buf[256];
    int t = threadIdx.x;
    int v = (t < nb) ? bsum[t] : 0;
    buf[t] = v;
    __syncthreads();
    for (int off = 1; off < 256; off <<= 1) {
        int add = (t >= off) ? buf[t - off] : 0;
        __syncthreads();
        buf[t] += add;
        __syncthreads();
    }
    if (t < nb) bsum[t] = buf[t] - v;   // exclusive
}

__global__ void k_scan_final(const int* __restrict__ deg, int n,
                             const int* __restrict__ bsum, int* __restrict__ rowptr) {
    __shared__ int buf[256];
    int t = threadIdx.x;
    int i = blockIdx.x * 256 + t;
    int v = (i < n) ? deg[i] : 0;
    buf[t] = v;
    __syncthreads();
    for (int off = 1; off < 256; off <<= 1) {
        int add = (t >= off) ? buf[t - off] : 0;
        __syncthreads();
        buf[t] += add;
        __syncthreads();
    }
    int excl = bsum[blockIdx.x] + buf[t] - v;
    if (i < n) rowptr[i] = excl;
    if (i == n - 1) rowptr[n] = excl + v;
}

__global__ void k_fill(const int* __restrict__ src, const int* __restrict__ dst, int E,
                       const int* __restrict__ rowptr, int* __restrict__ cursor,
                       int* __restrict__ col) {
    int e = blockIdx.x * blockDim.x + threadIdx.x;
    if (e < E) {
        int d = dst[e];
        int pos = atomicAdd(&cursor[d], 1);
        col[rowptr[d] + pos] = src[e];
    }
}

// ---------------- MFMA GEMM, layer 1: C[n,128] = A[n,256] @ W1 ----------------
// TA=float: in-register split A -> (ahi+alo); 3 products ahi*Bh + alo*Bh + ahi*Bl.
// TA=bf16:  A exact in bf16; 2 products a*Bh + a*Bl.
// Bth/Btl: [128 cols][256 k] bf16, row-major in k (contiguous fragment loads).
// block = 256 threads = 4 waves; tile = 32 rows x 128 cols; full K in regs.

template <typename TA>
__global__ void __launch_bounds__(256, 2)
k_gemm_mfma1(const TA* __restrict__ A, const __bf16* __restrict__ Bth,
             const __bf16* __restrict__ Btl, float* __restrict__ C, int n,
             const int* __restrict__ flag, int want) {
    if (want >= 0 && *flag != want) return;
    if (n <= 0) return;
    const int t = threadIdx.x;
    const int wave = t >> 6, lane = t & 63;
    const int l15 = lane & 15, lg = lane >> 4;
    const int row0 = blockIdx.x * 32;

    bf16x8_t bh[2][8], bl[2][8];
#pragma unroll
    for (int ct = 0; ct < 2; ct++) {
        const __bf16* bp = Bth + (size_t)(wave * 32 + ct * 16 + l15) * 256 + lg * 8;
        const __bf16* bq = Btl + (size_t)(wave * 32 + ct * 16 + l15) * 256 + lg * 8;
#pragma unroll
        for (int ks = 0; ks < 8; ks++) {
            bh[ct][ks] = *(const bf16x8_t*)(bp + ks * 32);
            bl[ct][ks] = *(const bf16x8_t*)(bq + ks * 32);
        }
    }

    int r0 = row0 + l15;      if (r0 > n - 1) r0 = n - 1;
    int r1 = row0 + 16 + l15; if (r1 > n - 1) r1 = n - 1;
    const TA* ap[2] = {A + (size_t)r0 * 256 + lg * 8, A + (size_t)r1 * 256 + lg * 8};

    f32x4_t acc[2][2];
#pragma unroll
    for (int rt = 0; rt < 2; rt++)
#pragma unroll
        for (int ct = 0; ct < 2; ct++)
            acc[rt][ct] = (f32x4_t){0.f, 0.f, 0.f, 0.f};

#pragma unroll
    for (int ks = 0; ks < 8; ks++) {
        bf16x8_t ah[2], al[2];
#pragma unroll
        for (int rt = 0; rt < 2; rt++) {
            if constexpr (std::is_same<TA, float>::value) {
                const float* p = ap[rt] + ks * 32;
                float4 v0 = *(const float4*)p;
                float4 v1 = *(const float4*)(p + 4);
                float v[8] = {v0.x, v0.y, v0.z, v0.w, v1.x, v1.y, v1.z, v1.w};
#pragma unroll
                for (int j = 0; j < 8; j++) {
                    __bf16 h = (__bf16)v[j];
                    ah[rt][j] = h;
                    al[rt][j] = (__bf16)(v[j] - (float)h);
                }
            } else {
                ah[rt] = *(const bf16x8_t*)(ap[rt] + ks * 32);
            }
        }
#pragma unroll
        for (int rt = 0; rt < 2; rt++)
#pragma unroll
            for (int ct = 0; ct < 2; ct++) {
                acc[rt][ct] = __builtin_amdgcn_mfma_f32_16x16x32_bf16(
                    ah[rt], bh[ct][ks], acc[rt][ct], 0, 0, 0);
                acc[rt][ct] = __builtin_amdgcn_mfma_f32_16x16x32_bf16(
                    ah[rt], bl[ct][ks], acc[rt][ct], 0, 0, 0);
                if constexpr (std::is_same<TA, float>::value)
                    acc[rt][ct] = __builtin_amdgcn_mfma_f32_16x16x32_bf16(
                        al[rt], bh[ct][ks], acc[rt][ct], 0, 0, 0);
            }
    }

    // C/D layout: col = lane&15, row = (lane>>4)*4 + reg
#pragma unroll
    for (int rt = 0; rt < 2; rt++) {
#pragma unroll
        for (int r = 0; r < 4; r++) {
            int row = row0 + rt * 16 + lg * 4 + r;
            if (row < n) {
#pragma unroll
                for (int ct = 0; ct < 2; ct++) {
                    int colx = wave * 32 + ct * 16 + l15;
                    C[(size_t)row * 128 + colx] = acc[rt][ct][r];
                }
            }
        }
    }
}

// ---------------- MFMA GEMM, layer 2: C[n,128] = (Ahi+Alo)[n,128] @ W2 ----------------
// A: [n][256] bf16 = [hi(128) | lo(128)] per row (written by k_agg OMODE 2).
// 3 products: ahi*Bh + alo*Bh + ahi*Bl. Bth/Btl: [128][128] bf16.

__global__ void __launch_bounds__(256, 2)
k_gemm_mfma2(const __bf16* __restrict__ A, const __bf16* __restrict__ Bth,
             const __bf16* __restrict__ Btl, float* __restrict__ C, int n) {
    if (n <= 0) return;
    const int t = threadIdx.x;
    const int wave = t >> 6, lane = t & 63;
    const int l15 = lane & 15, lg = lane >> 4;
    const int row0 = blockIdx.x * 32;

    bf16x8_t bh[2][4], bl[2][4];
#pragma unroll
    for (int ct = 0; ct < 2; ct++) {
        const __bf16* bp = Bth + (size_t)(wave * 32 + ct * 16 + l15) * 128 + lg * 8;
        const __bf16* bq = Btl + (size_t)(wave * 32 + ct * 16 + l15) * 128 + lg * 8;
#pragma unroll
        for (int ks = 0; ks < 4; ks++) {
            bh[ct][ks] = *(const bf16x8_t*)(bp + ks * 32);
            bl[ct][ks] = *(const bf16x8_t*)(bq + ks * 32);
        }
    }

    int r0 = row0 + l15;      if (r0 > n - 1) r0 = n - 1;
    int r1 = row0 + 16 + l15; if (r1 > n - 1) r1 = n - 1;
    const __bf16* ap[2] = {A + (size_t)r0 * 256 + lg * 8, A + (size_t)r1 * 256 + lg * 8};

    f32x4_t acc[2][2];
#pragma unroll
    for (int rt = 0; rt < 2; rt++)
#pragma unroll
        for (int ct = 0; ct < 2; ct++)
            acc[rt][ct] = (f32x4_t){0.f, 0.f, 0.f, 0.f};

#pragma unroll
    for (int ks = 0; ks < 4; ks++) {
        bf16x8_t ah[2], al[2];
#pragma unroll
        for (int rt = 0; rt < 2; rt++) {
            ah[rt] = *(const bf16x8_t*)(ap[rt] + ks * 32);
            al[rt] = *(const bf16x8_t*)(ap[rt] + 128 + ks * 32);
        }
#pragma unroll
        for (int rt = 0; rt < 2; rt++)
#pragma unroll
            for (int ct = 0; ct < 2; ct++) {
                acc[rt][ct] = __builtin_amdgcn_mfma_f32_16x16x32_bf16(
                    ah[rt], bh[ct][ks], acc[rt][ct], 0, 0, 0);
                acc[rt][ct] = __builtin_amdgcn_mfma_f32_16x16x32_bf16(
                    al[rt], bh[ct][ks], acc[rt][ct], 0, 0, 0);
                acc[rt][ct] = __builtin_amdgcn_mfma_f32_16x16x32_bf16(
                    ah[rt], bl[ct][ks], acc[rt][ct], 0, 0, 0);
            }
    }

#pragma unroll
    for (int rt = 0; rt < 2; rt++) {
#pragma unroll
        for (int r = 0; r < 4; r++) {
            int row = row0 + rt * 16 + lg * 4 + r;
            if (row < n) {
#pragma unroll
                for (int ct = 0; ct < 2; ct++) {
                    int colx = wave * 32 + ct * 16 + l15;
                    C[(size_t)row * 128 + colx] = acc[rt][ct][r];
                }
            }
        }
    }
}

// ---------------- attention coefficients: alpha_s/alpha_d [n,H] ----------------

template <int H, int C>
__global__ void k_alpha(const float* __restrict__ h, const float* __restrict__ a_src,
                        const float* __restrict__ a_dst, int n,
                        float* __restrict__ as, float* __restrict__ ad) {
    int i = blockIdx.x * blockDim.x + threadIdx.x;   // (node, head)
    if (i >= n * H) return;
    int node = i / H, hh = i - node * H;
    const float* hp = &h[(size_t)node * (H * C) + hh * C];
    float ss = 0.f, sd = 0.f;
#pragma unroll
    for (int c = 0; c < C; c++) {
        float v = hp[c];
        ss += v * a_src[hh * C + c];
        sd += v * a_dst[hh * C + c];
    }
    as[i] = ss;
    ad[i] = sd;
}

// ---------------- aggregation: softmax over incoming edges + weighted sum ----------------
// one block (128 threads) per destination node; H*C must be 128.
// OMODE: 0 = f32 out [n,128]; 1 = bf16 out [n,128]; 2 = split hi/lo bf16 out [n,256]
// (mode 2 feeds the layer-2 MFMA GEMM: hi = bf16(val), lo = bf16(val - hi))

template <int H, int C, bool ELU_OUT, int OMODE>
__global__ void k_agg(const float* __restrict__ feat,  // [n, H*C]
                      const float* __restrict__ as,    // [n, H]
                      const float* __restrict__ ad,    // [n, H]
                      const int* __restrict__ rowptr,
                      const int* __restrict__ col,
                      const float* __restrict__ bias,  // [H*C]
                      void* __restrict__ out_, int n,
                      const int* __restrict__ flag, int want) {
    if (want >= 0 && *flag != want) return;
    constexpr int HC_ = H * C;
    int node = blockIdx.x;
    int t = threadIdx.x;        // 0..127 channel id
    int h = t / C;
    __shared__ float p_lds[64 * H];
    __shared__ int src_lds[64];
    __shared__ float s_sh[H];
    __shared__ float ad_sh[H];
    if (t < H) ad_sh[t] = ad[node * H + t];
    __syncthreads();
    int begin = rowptr[node], end = rowptr[node + 1];
    int total = end - begin + 1;   // + self-loop (placed last)
    float acc = 0.f;
    float s_loc[H];
#pragma unroll
    for (int hh = 0; hh < H; hh++) s_loc[hh] = 0.f;
    for (int base = 0; base < total; base += 64) {
        int cl = min(64, total - base);
        if (t < 64) {
            int j = base + t;
            if (j < total) {
                int s = (j < total - 1) ? col[begin + j] : node;
                src_lds[t] = s;
#pragma unroll
                for (int hh = 0; hh < H; hh++) {
                    float e = as[s * H + hh] + ad_sh[hh];
                    e = (e > 0.f) ? e : 0.2f * e;
                    float p = __expf(e);
                    p_lds[t * H + hh] = p;
                    s_loc[hh] += p;
                }
            }
        }
        __syncthreads();
        for (int j = 0; j < cl; j++) {
            acc += p_lds[j * H + h] * feat[(size_t)src_lds[j] * HC_ + t];
        }
        __syncthreads();
    }
    if (t < 64) {
#pragma unroll
        for (int hh = 0; hh < H; hh++) {
            float v = s_loc[hh];
#pragma unroll
            for (int off = 32; off > 0; off >>= 1) v += __shfl_xor(v, off);
            if (t == 0) s_sh[hh] = v;
        }
    }
    __syncthreads();
    float val = acc / (s_sh[h] + 1e-16f) + bias[t];
    if (ELU_OUT) val = (val > 0.f) ? val : expm1f(val);
    if constexpr (OMODE == 0) {
        ((float*)out_)[(size_t)node * HC_ + t] = val;
    } else if constexpr (OMODE == 1) {
        ((bf16*)out_)[(size_t)node * HC_ + t] = __float2bfloat16(val);
    } else {
        __bf16 hi = (__bf16)val;
        __bf16* o = (__bf16*)out_;
        o[(size_t)node * (2 * HC_) + t] = hi;
        o[(size_t)node * (2 * HC_) + HC_ + t] = (__bf16)(val - (float)hi);
    }
}

// ---------------- launch ----------------

extern "C" void kernel_launch(void* const* d_in, const int* in_sizes, int n_in,
                              void* d_out, int out_size, void* d_ws, size_t ws_size,
                              hipStream_t stream) {
    const void* x  = d_in[0];
    const int*  ei = (const int*)d_in[1];

    int n = in_sizes[0] / IN_DIM;   // 50000
    int E = in_sizes[1] / 2;        // 800000
    const int* src = ei;
    const int* dst = ei + E;

    // workspace carve (256B aligned)
    char* w = (char*)d_ws;
    auto alloc = [&](size_t bytes) -> void* {
        void* p = (void*)w;
        w += (bytes + 255) / 256 * 256;
        return p;
    };
    int*    flag   = (int*)alloc(256);
    float*  w1f    = (float*)alloc((size_t)IN_DIM * HC * 4);
    float*  as1w   = (float*)alloc(HEADS * NHID * 4);
    float*  ad1w   = (float*)alloc(HEADS * NHID * 4);
    float*  b1f    = (float*)alloc(HC * 4);
    float*  w2f    = (float*)alloc((size_t)HC * OUT_DIM * 4);
    float*  as2w   = (float*)alloc(OUT_DIM * 4);
    float*  ad2w   = (float*)alloc(OUT_DIM * 4);
    float*  b2f    = (float*)alloc(OUT_DIM * 4);
    __bf16* b1th   = (__bf16*)alloc((size_t)128 * 256 * 2);   // W1^T hi bf16 [128][256]
    __bf16* b1tl   = (__bf16*)alloc((size_t)128 * 256 * 2);   // W1^T lo
    __bf16* b2th   = (__bf16*)alloc((size_t)128 * 128 * 2);   // W2^T hi bf16 [128][128]
    __bf16* b2tl   = (__bf16*)alloc((size_t)128 * 128 * 2);   // W2^T lo
    float*  h1     = (float*)alloc((size_t)n * HC * 4);   // layer1 features; reused as h2
    float*  hmid   = (float*)alloc((size_t)n * HC * 4);   // split-bf16 A2 [n][256] bf16 (aliased)
    float*  as1    = (float*)alloc((size_t)n * HEADS * 4);
    float*  ad1    = (float*)alloc((size_t)n * HEADS * 4);
    float*  as2    = (float*)alloc((size_t)n * 4);
    float*  ad2    = (float*)alloc((size_t)n * 4);
    int*    deg    = (int*)alloc((size_t)n * 4);
    int*    rowptr = (int*)alloc((size_t)(n + 1) * 4);
    int*    cursor = (int*)alloc((size_t)n * 4);
    int*    colv   = (int*)alloc((size_t)E * 4);
    int*    bsum   = (int*)alloc(256 * 4);
    float*  h2 = h1;               // reuse
    __bf16* a2 = (__bf16*)hmid;    // alias: [n][256] bf16 == [n][128] f32 in bytes

    k_detect<<<1, 256, 0, stream>>>((const unsigned int*)x, flag);

    // convert small weight tensors to fp32
    struct CvtJob { const void* in; float* out; int ne; };
    CvtJob jobs[8] = {
        {d_in[2], w1f,  IN_DIM * HC},
        {d_in[3], as1w, HEADS * NHID},
        {d_in[4], ad1w, HEADS * NHID},
        {d_in[5], b1f,  HC},
        {d_in[6], w2f,  HC * OUT_DIM},
        {d_in[7], as2w, OUT_DIM},
        {d_in[8], ad2w, OUT_DIM},
        {d_in[9], b2f,  OUT_DIM},
    };
    for (int j = 0; j < 8; j++)
        k_cvt<<<(jobs[j].ne + 255) / 256, 256, 0, stream>>>(jobs[j].in, jobs[j].out, jobs[j].ne, flag);

    // split-bf16 transposed weight panels
    k_prep_bt<<<(128 * 256 + 255) / 256, 256, 0, stream>>>(w1f, b1th, b1tl, 256);
    k_prep_bt<<<(128 * 128 + 255) / 256, 256, 0, stream>>>(w2f, b2th, b2tl, 128);

    hipMemsetAsync(deg, 0, (size_t)n * 4, stream);
    hipMemsetAsync(cursor, 0, (size_t)n * 4, stream);

    int nb = (n + 255) / 256;   // 196 <= 256
    k_degree<<<(E + 255) / 256, 256, 0, stream>>>(dst, E, deg);
    k_blocksum<<<nb, 256, 0, stream>>>(deg, n, bsum);
    k_scan_bsum<<<1, 256, 0, stream>>>(bsum, nb);
    k_scan_final<<<nb, 256, 0, stream>>>(deg, n, bsum, rowptr);
    k_fill<<<(E + 255) / 256, 256, 0, stream>>>(src, dst, E, rowptr, cursor, colv);

    // layer 1 — MFMA both paths (f32: in-register hi/lo split; bf16: direct)
    k_gemm_mfma1<bf16><<<(n + 31) / 32, 256, 0, stream>>>(
        (const bf16*)x, b1th, b1tl, h1, n, flag, 0);
    k_gemm_mfma1<float><<<(n + 31) / 32, 256, 0, stream>>>(
        (const float*)x, b1th, b1tl, h1, n, flag, 1);
    k_alpha<HEADS, NHID><<<((size_t)n * HEADS + 255) / 256, 256, 0, stream>>>(h1, as1w, ad1w, n, as1, ad1);
    // both paths: write split hi/lo bf16 A2 for the layer-2 MFMA GEMM
    k_agg<HEADS, NHID, true, 2><<<n, 128, 0, stream>>>(h1, as1, ad1, rowptr, colv, b1f, a2, n, flag, -1);

    // layer 2 — MFMA split-bf16, single launch
    k_gemm_mfma2<<<(n + 31) / 32, 256, 0, stream>>>(a2, b2th, b2tl, h2, n);
    k_alpha<1, OUT_DIM><<<(n + 255) / 256, 256, 0, stream>>>(h2, as2w, ad2w, n, as2, ad2);
    // output dual-launched on dtype (ref propagates input dtype to output)
    k_agg<1, OUT_DIM, false, 1><<<n, 128, 0, stream>>>(h2, as2, ad2, rowptr, colv, b2f, d_out, n, flag, 0);
    k_agg<1, OUT_DIM, false, 0><<<n, 128, 0, stream>>>(h2, as2, ad2, rowptr, colv, b2f, d_out, n, flag, 1);
}